// Round 1
// baseline (154.184 us; speedup 1.0000x reference)
//
#include <hip/hip_runtime.h>
#include <hip/hip_bf16.h>

#define BB 2
#define NN 20000
#define EE 200000
#define INF 256
#define OUTF 32
#define NH 4
#define HF 128          // NH*OUTF
#define NEG_SLOPE 0.2f
#define GEMM_BLOCKS 625  // 40000 rows / 64
#define EDGE_BLOCKS 782  // ceil(200000/256), 1 edge per thread
#define CAP 96           // slots per node (deg ~ Poisson(10); overflow -> list)
#define OVF_CAP 8192

using bf16 = __hip_bfloat16;
typedef __attribute__((ext_vector_type(8))) short bf16x8;
typedef __attribute__((ext_vector_type(4))) float f32x4;

__device__ __forceinline__ float bf2f(unsigned short s){ return __uint_as_float((unsigned)s << 16); }
__device__ __forceinline__ ushort f2bf_bits(float f){
    __hip_bfloat16 b = __float2bfloat16(f);
    return *(ushort*)&b;
}

__device__ __forceinline__ int get_src(const int* ei, int e, int f64){
    return f64 ? ei[2 * e] : ei[e];
}
__device__ __forceinline__ int get_dst(const int* ei, int e, int f64){
    return f64 ? ei[2 * EE + 2 * e] : ei[EE + e];
}

// K0: init cnt/last_e/ovf; blocks 0..15: dtype-detect (each block re-derives the
// flag from the same data -> deterministic) + W -> bf16 B-frag-linear wbf,
// one frag per thread (16 blocks x 256 threads = 4096 frags).
__global__ void k_init(const ushort* __restrict__ xr, const int* __restrict__ er,
                       const void* __restrict__ Wv,
                       int* __restrict__ flags, ushort* __restrict__ wbf,
                       int* __restrict__ cnt, int* __restrict__ last_e,
                       int* __restrict__ ovf_cnt){
    int i = blockIdx.x * blockDim.x + threadIdx.x;
    if (i < NN){ cnt[i] = 0; last_e[i] = -1; }
    if (i == 0) *ovf_cnt = 0;
    if (blockIdx.x < 16){
        __shared__ int cnt_big, cnt_nz;
        if (threadIdx.x == 0){ cnt_big = 0; cnt_nz = 0; }
        __syncthreads();
        int big = 0;
        for (int k = threadIdx.x; k < 8192; k += blockDim.x){
            unsigned e = ((unsigned)xr[2 * k] >> 7) & 0xff;   // bf16-exp of fp32 low half
            if (e >= 0xC0) big++;                              // impossible for N(0,1) bf16
        }
        int nz = 0;
        for (int k = threadIdx.x; k < 4096; k += blockDim.x){
            if (er[2 * k + 1] != 0) nz++;                      // int64 high words all zero
        }
        atomicAdd(&cnt_big, big);
        atomicAdd(&cnt_nz, nz);
        __syncthreads();
        if (blockIdx.x == 0 && threadIdx.x == 0){
            flags[0] = (cnt_big >= 16) ? 1 : 0;
            flags[1] = (cnt_nz == 0) ? 1 : 0;
        }
        const bool f32w = (cnt_big >= 16);
        int fr = blockIdx.x * 256 + threadIdx.x;               // 0..4095
        {
            int lane = fr & 63;
            int t    = (fr >> 6) & 3;
            int kc   = (fr >> 8) & 7;
            int ch   = fr >> 11;
            int col  = ch * 64 + t * 16 + (lane & 15);
            int kb   = kc * 32 + (lane >> 4) * 8;
            bf16x8 v;
            if (f32w){
                const float* wg = (const float*)Wv + (size_t)col * INF + kb;
                #pragma unroll
                for (int j = 0; j < 8; ++j) v[j] = (short)f2bf_bits(wg[j]);
            } else {
                const ushort* wg = (const ushort*)Wv + (size_t)col * INF + kb;
                #pragma unroll
                for (int j = 0; j < 8; ++j) v[j] = (short)wg[j];
            }
            *(bf16x8*)(wbf + (size_t)fr * 8) = v;
        }
    }
}

// K1: edge blocks FIRST (1 edge/thread, full TLP, overlaps GEMM); then MFMA GEMM,
// one wave = 16 rows x BOTH col-halves (x read once, 64 MFMAs/wave).
__global__ __launch_bounds__(256, 4)
void k_gemm(const void* __restrict__ xv_, const ushort* __restrict__ wbf,
            const void* __restrict__ av, const int* __restrict__ ei,
            const int* __restrict__ flags, ushort* __restrict__ h,
            float* __restrict__ alpha_s, float* __restrict__ alpha_d,
            int* __restrict__ last_e, int* __restrict__ cnt,
            ushort* __restrict__ slots, int* __restrict__ ovf_cnt,
            int* __restrict__ ovf_list){
    if (blockIdx.x < EDGE_BLOCKS){
        int f64 = flags[1];
        int e = blockIdx.x * 256 + threadIdx.x;
        if (e < EE){
            int s = get_src(ei, e, f64);
            int d = get_dst(ei, e, f64);
            atomicMax(&last_e[s], e);
            int idx = atomicAdd(&cnt[s], 1);
            if (idx < CAP) slots[(size_t)s * CAP + idx] = (ushort)d;
            else { int o = atomicAdd(ovf_cnt, 1); if (o < OVF_CAP) ovf_list[o] = e; }
        }
        return;
    }

    const int bid  = blockIdx.x - EDGE_BLOCKS;
    const int tid  = threadIdx.x;
    const int lane = tid & 63;
    const int w    = tid >> 6;            // wave 0..3
    const int l15  = lane & 15;
    const int q    = lane >> 4;           // quad 0..3
    const bool f32 = flags[0] != 0;

    const int row0 = bid * 64 + w * 16;   // wave's 16 rows

    f32x4 acc[2][4];
    #pragma unroll
    for (int c = 0; c < 2; ++c)
        #pragma unroll
        for (int t = 0; t < 4; ++t) acc[c][t] = (f32x4){0.f, 0.f, 0.f, 0.f};

    if (f32){
        const float* xp = (const float*)xv_ + (size_t)(row0 + l15) * INF + q * 8;
        float4 raw[8][2];
        #pragma unroll
        for (int kc = 0; kc < 8; ++kc){                // all loads in flight
            const float4* p = (const float4*)(xp + kc * 32);
            raw[kc][0] = p[0];
            raw[kc][1] = p[1];
        }
        #pragma unroll
        for (int kc = 0; kc < 8; ++kc){
            float4 lo = raw[kc][0], hi = raw[kc][1];
            bf16x8 afrag;
            afrag[0] = (short)f2bf_bits(lo.x); afrag[1] = (short)f2bf_bits(lo.y);
            afrag[2] = (short)f2bf_bits(lo.z); afrag[3] = (short)f2bf_bits(lo.w);
            afrag[4] = (short)f2bf_bits(hi.x); afrag[5] = (short)f2bf_bits(hi.y);
            afrag[6] = (short)f2bf_bits(hi.z); afrag[7] = (short)f2bf_bits(hi.w);
            #pragma unroll
            for (int c = 0; c < 2; ++c){
                const ushort* wb = wbf + (size_t)c * 16384;
                #pragma unroll
                for (int t = 0; t < 4; ++t){
                    bf16x8 bfrag = *(const bf16x8*)(wb + (((size_t)kc * 4 + t) * 64 + lane) * 8);
                    acc[c][t] = __builtin_amdgcn_mfma_f32_16x16x32_bf16(afrag, bfrag, acc[c][t], 0, 0, 0);
                }
            }
        }
    } else {
        const ushort* xp = (const ushort*)xv_ + (size_t)(row0 + l15) * INF + q * 8;
        #pragma unroll
        for (int kc = 0; kc < 8; ++kc){
            bf16x8 afrag = *(const bf16x8*)(xp + kc * 32);
            #pragma unroll
            for (int c = 0; c < 2; ++c){
                const ushort* wb = wbf + (size_t)c * 16384;
                #pragma unroll
                for (int t = 0; t < 4; ++t){
                    bf16x8 bfrag = *(const bf16x8*)(wb + (((size_t)kc * 4 + t) * 64 + lane) * 8);
                    acc[c][t] = __builtin_amdgcn_mfma_f32_16x16x32_bf16(afrag, bfrag, acc[c][t], 0, 0, 0);
                }
            }
        }
    }

    // ---- epilogue 1: h -> bf16, f-major [row][f*4+hd]; both col-halves -> one 8B store ----
    #pragma unroll
    for (int r = 0; r < 4; ++r){
        int row = row0 + q * 4 + r;
        #pragma unroll
        for (int t = 0; t < 2; ++t){    // t = f-half; f = t*16 + l15
            unsigned v0 = (unsigned)f2bf_bits(acc[0][t][r])
                        | ((unsigned)f2bf_bits(acc[0][t + 2][r]) << 16);  // heads 0,1
            unsigned v1 = (unsigned)f2bf_bits(acc[1][t][r])
                        | ((unsigned)f2bf_bits(acc[1][t + 2][r]) << 16);  // heads 2,3
            int f = t * 16 + l15;
            uint2 vv; vv.x = v0; vv.y = v1;
            *(uint2*)(h + (size_t)row * HF + f * 4) = vv;
        }
    }

    // ---- epilogue 2: alpha dots from C registers ----
    float as_lo, as_hi, ad_lo, ad_hi;
    if (f32){
        const float* af = (const float*)av;
        as_lo = af[l15];        as_hi = af[16 + l15];
        ad_lo = af[OUTF + l15]; ad_hi = af[OUTF + 16 + l15];
    } else {
        const ushort* ab = (const ushort*)av;
        as_lo = bf2f(ab[l15]);        as_hi = bf2f(ab[16 + l15]);
        ad_lo = bf2f(ab[OUTF + l15]); ad_hi = bf2f(ab[OUTF + 16 + l15]);
    }
    #pragma unroll
    for (int r = 0; r < 4; ++r){
        int row = row0 + q * 4 + r;
        #pragma unroll
        for (int c = 0; c < 2; ++c){
            #pragma unroll
            for (int hp = 0; hp < 2; ++hp){
                int t0 = hp * 2, t1 = hp * 2 + 1;
                float ps = acc[c][t0][r] * as_lo + acc[c][t1][r] * as_hi;
                float pd = acc[c][t0][r] * ad_lo + acc[c][t1][r] * ad_hi;
                ps += __shfl_down(ps, 8, 16); pd += __shfl_down(pd, 8, 16);
                ps += __shfl_down(ps, 4, 16); pd += __shfl_down(pd, 4, 16);
                ps += __shfl_down(ps, 2, 16); pd += __shfl_down(pd, 2, 16);
                ps += __shfl_down(ps, 1, 16); pd += __shfl_down(pd, 1, 16);
                if (l15 == 0){
                    size_t o = (size_t)row * NH + c * 2 + hp;
                    alpha_s[o] = ps;
                    alpha_d[o] = pd;
                }
            }
        }
    }
}

// K2 (fused aw+agg): one wave per node. Lanes 0..7 groups compute the per-(b,h)
// batch softmax at the last edge (replicated every 8 lanes), broadcast via shfl;
// aw also written to global for k_fix. Then atomic-free bucket aggregate.
__global__ __launch_bounds__(256)
void k_agg(const ushort* __restrict__ slots, const int* __restrict__ cnt,
           const int* __restrict__ last_e, const int* __restrict__ ei,
           const int* __restrict__ flags,
           const float* __restrict__ alpha_s, const float* __restrict__ alpha_d,
           const ushort* __restrict__ h, float* __restrict__ aw,
           float* __restrict__ out_f){
    int lane = threadIdx.x & 63;
    int wid  = (blockIdx.x * blockDim.x + threadIdx.x) >> 6;
    int nw   = (gridDim.x * blockDim.x) >> 6;
    int b = lane >> 5;
    int f = lane & 31;
    int c  = lane & 7;          // softmax work item: bb = c>>2, hh = c&3
    int bb = c >> 2;
    int hh = c & 3;
    int f64 = flags[1];
    for (int n = wid; n < NN; n += nw){
        int m  = cnt[n]; if (m > CAP) m = CAP;
        int le = last_e[n];

        // per-(bb,hh) attention weight (replicated x8 across the wave)
        float my_aw = 0.f;
        if (le >= 0){
            int d = get_dst(ei, le, f64);
            float ss = alpha_s[((size_t)bb * NN + n) * NH + hh]
                     + alpha_d[((size_t)bb * NN + d) * NH + hh];
            float so = alpha_s[((size_t)(1 - bb) * NN + n) * NH + hh]
                     + alpha_d[((size_t)(1 - bb) * NN + d) * NH + hh];
            ss = ss > 0.f ? ss : NEG_SLOPE * ss;
            so = so > 0.f ? so : NEG_SLOPE * so;
            float mx = fmaxf(ss, so);
            float e0 = __expf(ss - mx);
            float e1 = __expf(so - mx);
            my_aw = 0.25f * e0 / (e0 + e1);
        }
        if (lane < 8) aw[((size_t)bb * NN + n) * NH + hh] = my_aw;  // for k_fix

        float aw0 = __shfl(my_aw, (b << 2) + 0, 8);
        float aw1 = __shfl(my_aw, (b << 2) + 1, 8);
        float aw2 = __shfl(my_aw, (b << 2) + 2, 8);
        float aw3 = __shfl(my_aw, (b << 2) + 3, 8);

        const ushort* sl = slots + (size_t)n * CAP;
        const ushort* hb = h + (size_t)b * NN * HF + f * 4;
        float ax = 0.f, ay = 0.f, az = 0.f, aww = 0.f;
        int i = 0;
        for (; i + 4 <= m; i += 4){
            ushort4 dd = *(const ushort4*)(sl + i);     // uniform 8B broadcast
            ushort4 u0 = *(const ushort4*)(hb + (size_t)dd.x * HF);
            ushort4 u1 = *(const ushort4*)(hb + (size_t)dd.y * HF);
            ushort4 u2 = *(const ushort4*)(hb + (size_t)dd.z * HF);
            ushort4 u3 = *(const ushort4*)(hb + (size_t)dd.w * HF);
            ax += bf2f(u0.x) + bf2f(u1.x) + bf2f(u2.x) + bf2f(u3.x);
            ay += bf2f(u0.y) + bf2f(u1.y) + bf2f(u2.y) + bf2f(u3.y);
            az += bf2f(u0.z) + bf2f(u1.z) + bf2f(u2.z) + bf2f(u3.z);
            aww += bf2f(u0.w) + bf2f(u1.w) + bf2f(u2.w) + bf2f(u3.w);
        }
        for (; i < m; ++i){
            ushort4 u = *(const ushort4*)(hb + (size_t)sl[i] * HF);
            ax += bf2f(u.x); ay += bf2f(u.y); az += bf2f(u.z); aww += bf2f(u.w);
        }
        out_f[((size_t)b * NN + n) * OUTF + f] =
            aw0 * ax + aw1 * ay + aw2 * az + aw3 * aww;
    }
}

// K4: overflow fix-up (normally empty). One wave per overflow edge, atomics.
__global__ void k_fix(const int* __restrict__ ei, const int* __restrict__ flags,
                      const int* __restrict__ ovf_cnt, const int* __restrict__ ovf_list,
                      const ushort* __restrict__ h, const float* __restrict__ aw,
                      float* __restrict__ out_f){
    int lane = threadIdx.x & 63;
    int wid  = (blockIdx.x * blockDim.x + threadIdx.x) >> 6;
    int nw   = (gridDim.x * blockDim.x) >> 6;
    int b = lane >> 5;
    int f = lane & 31;
    int M = *ovf_cnt; if (M > OVF_CAP) M = OVF_CAP;
    int f64 = flags[1];
    for (int i = wid; i < M; i += nw){
        int e = ovf_list[i];
        int s = get_src(ei, e, f64);
        int d = get_dst(ei, e, f64);
        float4 awv = *(const float4*)(aw + ((size_t)b * NN + s) * NH);
        ushort4 u = *(const ushort4*)(h + ((size_t)b * NN + d) * HF + f * 4);
        float acc = awv.x * bf2f(u.x) + awv.y * bf2f(u.y)
                  + awv.z * bf2f(u.z) + awv.w * bf2f(u.w);
        atomicAdd(&out_f[((size_t)b * NN + s) * OUTF + f], acc);
    }
}

extern "C" void kernel_launch(void* const* d_in, const int* in_sizes, int n_in,
                              void* d_out, int out_size, void* d_ws, size_t ws_size,
                              hipStream_t stream){
    const void* x = d_in[0]; const void* eiv = d_in[1];
    const void* W = d_in[2]; const void* a  = d_in[3];
    for (int i = 0; i < n_in; ++i){
        if      (in_sizes[i] == BB * NN * INF) x   = d_in[i];
        else if (in_sizes[i] == 2 * EE)        eiv = d_in[i];
        else if (in_sizes[i] == HF * INF)      W   = d_in[i];
        else if (in_sizes[i] == 2 * OUTF)      a   = d_in[i];
    }
    const int* ei = (const int*)eiv;
    float* out = (float*)d_out;    // output dtype: float32 (verified round 3)

    // Workspace (~15.5 MiB): flags | wbf | h | alpha_s | alpha_d | aw | last_e
    //                        | cnt | ovf_cnt | ovf_list | slots
    const size_t HN = (size_t)BB * NN * HF;
    char* p = (char*)d_ws;
    int*    flags    = (int*)p;                       p += 64;
    ushort* wbf      = (ushort*)p;                    p += 32768 * 2;
    ushort* h        = (ushort*)p;                    p += HN * 2;
    float*  alpha_s  = (float*)p;                     p += (size_t)BB * NN * NH * 4;
    float*  alpha_d  = (float*)p;                     p += (size_t)BB * NN * NH * 4;
    float*  aw       = (float*)p;                     p += (size_t)BB * NN * NH * 4;
    int*    last_e   = (int*)p;                       p += (size_t)NN * 4;
    int*    cnt      = (int*)p;                       p += (size_t)NN * 4;
    int*    ovf_cnt  = (int*)p;                       p += 64;
    int*    ovf_list = (int*)p;                       p += (size_t)OVF_CAP * 4;
    ushort* slots    = (ushort*)p;

    k_init <<<(NN + 255) / 256, 256, 0, stream>>>((const ushort*)x, ei, W, flags, wbf,
                                                  cnt, last_e, ovf_cnt);
    k_gemm <<<EDGE_BLOCKS + GEMM_BLOCKS, 256, 0, stream>>>(x, wbf, a, ei, flags, h,
                                                           alpha_s, alpha_d, last_e,
                                                           cnt, slots, ovf_cnt, ovf_list);
    k_agg  <<<2048, 256, 0, stream>>>(slots, cnt, last_e, ei, flags,
                                      alpha_s, alpha_d, h, aw, out);
    k_fix  <<<32, 256, 0, stream>>>(ei, flags, ovf_cnt, ovf_list, h, aw, out);
}

// Round 2
// 153.565 us; speedup vs baseline: 1.0040x; 1.0040x over previous
//
#include <hip/hip_runtime.h>
#include <hip/hip_bf16.h>

#define BB 2
#define NN 20000
#define EE 200000
#define INF 256
#define OUTF 32
#define NH 4
#define HF 128          // NH*OUTF
#define NEG_SLOPE 0.2f
#define GEMM_BLOCKS 625  // 40000 rows / 64
#define EDGE_BLOCKS 782  // ceil(200000/256), 1 edge per thread
#define CAP 96           // slots per node (deg ~ Poisson(10); overflow -> list)
#define OVF_CAP 8192

using bf16 = __hip_bfloat16;
typedef __attribute__((ext_vector_type(8))) short bf16x8;
typedef __attribute__((ext_vector_type(4))) float f32x4;

__device__ __forceinline__ float bf2f(unsigned short s){ return __uint_as_float((unsigned)s << 16); }
__device__ __forceinline__ ushort f2bf_bits(float f){
    __hip_bfloat16 b = __float2bfloat16(f);
    return *(ushort*)&b;
}

__device__ __forceinline__ int get_src(const int* ei, int e, int f64){
    return f64 ? ei[2 * e] : ei[e];
}
__device__ __forceinline__ int get_dst(const int* ei, int e, int f64){
    return f64 ? ei[2 * EE + 2 * e] : ei[EE + e];
}

// K0: init cnt/last_e/ovf; blocks 0..15: dtype-detect (each block re-derives the
// flag from the same data -> deterministic) + W -> bf16 B-frag-linear wbf,
// one frag per thread (16 blocks x 256 threads = 4096 frags).
__global__ void k_init(const ushort* __restrict__ xr, const int* __restrict__ er,
                       const void* __restrict__ Wv,
                       int* __restrict__ flags, ushort* __restrict__ wbf,
                       int* __restrict__ cnt, int* __restrict__ last_e,
                       int* __restrict__ ovf_cnt){
    int i = blockIdx.x * blockDim.x + threadIdx.x;
    if (i < NN){ cnt[i] = 0; last_e[i] = -1; }
    if (i == 0) *ovf_cnt = 0;
    if (blockIdx.x < 16){
        __shared__ int cnt_big, cnt_nz;
        if (threadIdx.x == 0){ cnt_big = 0; cnt_nz = 0; }
        __syncthreads();
        int big = 0;
        for (int k = threadIdx.x; k < 8192; k += blockDim.x){
            unsigned e = ((unsigned)xr[2 * k] >> 7) & 0xff;   // bf16-exp of fp32 low half
            if (e >= 0xC0) big++;                              // impossible for N(0,1) bf16
        }
        int nz = 0;
        for (int k = threadIdx.x; k < 4096; k += blockDim.x){
            if (er[2 * k + 1] != 0) nz++;                      // int64 high words all zero
        }
        atomicAdd(&cnt_big, big);
        atomicAdd(&cnt_nz, nz);
        __syncthreads();
        if (blockIdx.x == 0 && threadIdx.x == 0){
            flags[0] = (cnt_big >= 16) ? 1 : 0;
            flags[1] = (cnt_nz == 0) ? 1 : 0;
        }
        const bool f32w = (cnt_big >= 16);
        int fr = blockIdx.x * 256 + threadIdx.x;               // 0..4095
        {
            int lane = fr & 63;
            int t    = (fr >> 6) & 3;
            int kc   = (fr >> 8) & 7;
            int ch   = fr >> 11;
            int col  = ch * 64 + t * 16 + (lane & 15);
            int kb   = kc * 32 + (lane >> 4) * 8;
            bf16x8 v;
            if (f32w){
                const float* wg = (const float*)Wv + (size_t)col * INF + kb;
                #pragma unroll
                for (int j = 0; j < 8; ++j) v[j] = (short)f2bf_bits(wg[j]);
            } else {
                const ushort* wg = (const ushort*)Wv + (size_t)col * INF + kb;
                #pragma unroll
                for (int j = 0; j < 8; ++j) v[j] = (short)wg[j];
            }
            *(bf16x8*)(wbf + (size_t)fr * 8) = v;
        }
    }
}

// K1: edge blocks FIRST (1 edge/thread, full TLP, overlaps GEMM); then MFMA GEMM,
// one wave = 16 rows x BOTH col-halves. f32 x-path: static 1-deep register
// pipeline (NO bulk raw[8][2] -> no scratch spill; all indexing compile-time).
__global__ __launch_bounds__(256, 2)
void k_gemm(const void* __restrict__ xv_, const ushort* __restrict__ wbf,
            const void* __restrict__ av, const int* __restrict__ ei,
            const int* __restrict__ flags, ushort* __restrict__ h,
            float* __restrict__ alpha_s, float* __restrict__ alpha_d,
            int* __restrict__ last_e, int* __restrict__ cnt,
            ushort* __restrict__ slots, int* __restrict__ ovf_cnt,
            int* __restrict__ ovf_list){
    if (blockIdx.x < EDGE_BLOCKS){
        int f64 = flags[1];
        int e = blockIdx.x * 256 + threadIdx.x;
        if (e < EE){
            int s = get_src(ei, e, f64);
            int d = get_dst(ei, e, f64);
            atomicMax(&last_e[s], e);
            int idx = atomicAdd(&cnt[s], 1);
            if (idx < CAP) slots[(size_t)s * CAP + idx] = (ushort)d;
            else { int o = atomicAdd(ovf_cnt, 1); if (o < OVF_CAP) ovf_list[o] = e; }
        }
        return;
    }

    const int bid  = blockIdx.x - EDGE_BLOCKS;
    const int tid  = threadIdx.x;
    const int lane = tid & 63;
    const int w    = tid >> 6;            // wave 0..3
    const int l15  = lane & 15;
    const int q    = lane >> 4;           // quad 0..3
    const bool f32 = flags[0] != 0;

    const int row0 = bid * 64 + w * 16;   // wave's 16 rows

    f32x4 acc[2][4];
    #pragma unroll
    for (int c = 0; c < 2; ++c)
        #pragma unroll
        for (int t = 0; t < 4; ++t) acc[c][t] = (f32x4){0.f, 0.f, 0.f, 0.f};

    if (f32){
        const float* xp = (const float*)xv_ + (size_t)(row0 + l15) * INF + q * 8;
        // 1-deep pipeline: cur pair in regs, next pair in flight. 16 VGPRs total.
        float4 c0 = ((const float4*)xp)[0];
        float4 c1 = ((const float4*)xp)[1];
        #pragma unroll
        for (int kc = 0; kc < 8; ++kc){
            float4 n0, n1;
            if (kc < 7){
                const float4* p = (const float4*)(xp + (kc + 1) * 32);
                n0 = p[0];
                n1 = p[1];
            }
            bf16x8 afrag;
            afrag[0] = (short)f2bf_bits(c0.x); afrag[1] = (short)f2bf_bits(c0.y);
            afrag[2] = (short)f2bf_bits(c0.z); afrag[3] = (short)f2bf_bits(c0.w);
            afrag[4] = (short)f2bf_bits(c1.x); afrag[5] = (short)f2bf_bits(c1.y);
            afrag[6] = (short)f2bf_bits(c1.z); afrag[7] = (short)f2bf_bits(c1.w);
            #pragma unroll
            for (int c = 0; c < 2; ++c){
                const ushort* wb = wbf + (size_t)c * 16384;
                #pragma unroll
                for (int t = 0; t < 4; ++t){
                    bf16x8 bfrag = *(const bf16x8*)(wb + (((size_t)kc * 4 + t) * 64 + lane) * 8);
                    acc[c][t] = __builtin_amdgcn_mfma_f32_16x16x32_bf16(afrag, bfrag, acc[c][t], 0, 0, 0);
                }
            }
            if (kc < 7){ c0 = n0; c1 = n1; }
        }
    } else {
        const ushort* xp = (const ushort*)xv_ + (size_t)(row0 + l15) * INF + q * 8;
        bf16x8 af = *(const bf16x8*)xp;
        #pragma unroll
        for (int kc = 0; kc < 8; ++kc){
            bf16x8 nf;
            if (kc < 7) nf = *(const bf16x8*)(xp + (kc + 1) * 32);
            #pragma unroll
            for (int c = 0; c < 2; ++c){
                const ushort* wb = wbf + (size_t)c * 16384;
                #pragma unroll
                for (int t = 0; t < 4; ++t){
                    bf16x8 bfrag = *(const bf16x8*)(wb + (((size_t)kc * 4 + t) * 64 + lane) * 8);
                    acc[c][t] = __builtin_amdgcn_mfma_f32_16x16x32_bf16(af, bfrag, acc[c][t], 0, 0, 0);
                }
            }
            if (kc < 7) af = nf;
        }
    }

    // ---- epilogue 1: h -> bf16, f-major [row][f*4+hd]; both col-halves -> one 8B store ----
    #pragma unroll
    for (int r = 0; r < 4; ++r){
        int row = row0 + q * 4 + r;
        #pragma unroll
        for (int t = 0; t < 2; ++t){    // t = f-half; f = t*16 + l15
            unsigned v0 = (unsigned)f2bf_bits(acc[0][t][r])
                        | ((unsigned)f2bf_bits(acc[0][t + 2][r]) << 16);  // heads 0,1
            unsigned v1 = (unsigned)f2bf_bits(acc[1][t][r])
                        | ((unsigned)f2bf_bits(acc[1][t + 2][r]) << 16);  // heads 2,3
            int f = t * 16 + l15;
            uint2 vv; vv.x = v0; vv.y = v1;
            *(uint2*)(h + (size_t)row * HF + f * 4) = vv;
        }
    }

    // ---- epilogue 2: alpha dots from C registers ----
    float as_lo, as_hi, ad_lo, ad_hi;
    if (f32){
        const float* af = (const float*)av;
        as_lo = af[l15];        as_hi = af[16 + l15];
        ad_lo = af[OUTF + l15]; ad_hi = af[OUTF + 16 + l15];
    } else {
        const ushort* ab = (const ushort*)av;
        as_lo = bf2f(ab[l15]);        as_hi = bf2f(ab[16 + l15]);
        ad_lo = bf2f(ab[OUTF + l15]); ad_hi = bf2f(ab[OUTF + 16 + l15]);
    }
    #pragma unroll
    for (int r = 0; r < 4; ++r){
        int row = row0 + q * 4 + r;
        #pragma unroll
        for (int c = 0; c < 2; ++c){
            #pragma unroll
            for (int hp = 0; hp < 2; ++hp){
                int t0 = hp * 2, t1 = hp * 2 + 1;
                float ps = acc[c][t0][r] * as_lo + acc[c][t1][r] * as_hi;
                float pd = acc[c][t0][r] * ad_lo + acc[c][t1][r] * ad_hi;
                ps += __shfl_down(ps, 8, 16); pd += __shfl_down(pd, 8, 16);
                ps += __shfl_down(ps, 4, 16); pd += __shfl_down(pd, 4, 16);
                ps += __shfl_down(ps, 2, 16); pd += __shfl_down(pd, 2, 16);
                ps += __shfl_down(ps, 1, 16); pd += __shfl_down(pd, 1, 16);
                if (l15 == 0){
                    size_t o = (size_t)row * NH + c * 2 + hp;
                    alpha_s[o] = ps;
                    alpha_d[o] = pd;
                }
            }
        }
    }
}

// K2 (fused aw+agg): one wave per node. Lanes 0..7 groups compute the per-(b,h)
// batch softmax at the last edge (replicated every 8 lanes), broadcast via shfl;
// aw also written to global for k_fix. Then atomic-free bucket aggregate.
__global__ __launch_bounds__(256)
void k_agg(const ushort* __restrict__ slots, const int* __restrict__ cnt,
           const int* __restrict__ last_e, const int* __restrict__ ei,
           const int* __restrict__ flags,
           const float* __restrict__ alpha_s, const float* __restrict__ alpha_d,
           const ushort* __restrict__ h, float* __restrict__ aw,
           float* __restrict__ out_f){
    int lane = threadIdx.x & 63;
    int wid  = (blockIdx.x * blockDim.x + threadIdx.x) >> 6;
    int nw   = (gridDim.x * blockDim.x) >> 6;
    int b = lane >> 5;
    int f = lane & 31;
    int c  = lane & 7;          // softmax work item: bb = c>>2, hh = c&3
    int bb = c >> 2;
    int hh = c & 3;
    int f64 = flags[1];
    for (int n = wid; n < NN; n += nw){
        int m  = cnt[n]; if (m > CAP) m = CAP;
        int le = last_e[n];

        // per-(bb,hh) attention weight (replicated x8 across the wave)
        float my_aw = 0.f;
        if (le >= 0){
            int d = get_dst(ei, le, f64);
            float ss = alpha_s[((size_t)bb * NN + n) * NH + hh]
                     + alpha_d[((size_t)bb * NN + d) * NH + hh];
            float so = alpha_s[((size_t)(1 - bb) * NN + n) * NH + hh]
                     + alpha_d[((size_t)(1 - bb) * NN + d) * NH + hh];
            ss = ss > 0.f ? ss : NEG_SLOPE * ss;
            so = so > 0.f ? so : NEG_SLOPE * so;
            float mx = fmaxf(ss, so);
            float e0 = __expf(ss - mx);
            float e1 = __expf(so - mx);
            my_aw = 0.25f * e0 / (e0 + e1);
        }
        if (lane < 8) aw[((size_t)bb * NN + n) * NH + hh] = my_aw;  // for k_fix

        float aw0 = __shfl(my_aw, (b << 2) + 0, 8);
        float aw1 = __shfl(my_aw, (b << 2) + 1, 8);
        float aw2 = __shfl(my_aw, (b << 2) + 2, 8);
        float aw3 = __shfl(my_aw, (b << 2) + 3, 8);

        const ushort* sl = slots + (size_t)n * CAP;
        const ushort* hb = h + (size_t)b * NN * HF + f * 4;
        float ax = 0.f, ay = 0.f, az = 0.f, aww = 0.f;
        int i = 0;
        for (; i + 4 <= m; i += 4){
            ushort4 dd = *(const ushort4*)(sl + i);     // uniform 8B broadcast
            ushort4 u0 = *(const ushort4*)(hb + (size_t)dd.x * HF);
            ushort4 u1 = *(const ushort4*)(hb + (size_t)dd.y * HF);
            ushort4 u2 = *(const ushort4*)(hb + (size_t)dd.z * HF);
            ushort4 u3 = *(const ushort4*)(hb + (size_t)dd.w * HF);
            ax += bf2f(u0.x) + bf2f(u1.x) + bf2f(u2.x) + bf2f(u3.x);
            ay += bf2f(u0.y) + bf2f(u1.y) + bf2f(u2.y) + bf2f(u3.y);
            az += bf2f(u0.z) + bf2f(u1.z) + bf2f(u2.z) + bf2f(u3.z);
            aww += bf2f(u0.w) + bf2f(u1.w) + bf2f(u2.w) + bf2f(u3.w);
        }
        for (; i < m; ++i){
            ushort4 u = *(const ushort4*)(hb + (size_t)sl[i] * HF);
            ax += bf2f(u.x); ay += bf2f(u.y); az += bf2f(u.z); aww += bf2f(u.w);
        }
        out_f[((size_t)b * NN + n) * OUTF + f] =
            aw0 * ax + aw1 * ay + aw2 * az + aw3 * aww;
    }
}

// K4: overflow fix-up (normally empty). One wave per overflow edge, atomics.
__global__ void k_fix(const int* __restrict__ ei, const int* __restrict__ flags,
                      const int* __restrict__ ovf_cnt, const int* __restrict__ ovf_list,
                      const ushort* __restrict__ h, const float* __restrict__ aw,
                      float* __restrict__ out_f){
    int lane = threadIdx.x & 63;
    int wid  = (blockIdx.x * blockDim.x + threadIdx.x) >> 6;
    int nw   = (gridDim.x * blockDim.x) >> 6;
    int b = lane >> 5;
    int f = lane & 31;
    int M = *ovf_cnt; if (M > OVF_CAP) M = OVF_CAP;
    int f64 = flags[1];
    for (int i = wid; i < M; i += nw){
        int e = ovf_list[i];
        int s = get_src(ei, e, f64);
        int d = get_dst(ei, e, f64);
        float4 awv = *(const float4*)(aw + ((size_t)b * NN + s) * NH);
        ushort4 u = *(const ushort4*)(h + ((size_t)b * NN + d) * HF + f * 4);
        float acc = awv.x * bf2f(u.x) + awv.y * bf2f(u.y)
                  + awv.z * bf2f(u.z) + awv.w * bf2f(u.w);
        atomicAdd(&out_f[((size_t)b * NN + s) * OUTF + f], acc);
    }
}

extern "C" void kernel_launch(void* const* d_in, const int* in_sizes, int n_in,
                              void* d_out, int out_size, void* d_ws, size_t ws_size,
                              hipStream_t stream){
    const void* x = d_in[0]; const void* eiv = d_in[1];
    const void* W = d_in[2]; const void* a  = d_in[3];
    for (int i = 0; i < n_in; ++i){
        if      (in_sizes[i] == BB * NN * INF) x   = d_in[i];
        else if (in_sizes[i] == 2 * EE)        eiv = d_in[i];
        else if (in_sizes[i] == HF * INF)      W   = d_in[i];
        else if (in_sizes[i] == 2 * OUTF)      a   = d_in[i];
    }
    const int* ei = (const int*)eiv;
    float* out = (float*)d_out;    // output dtype: float32 (verified round 3)

    // Workspace (~15.5 MiB): flags | wbf | h | alpha_s | alpha_d | aw | last_e
    //                        | cnt | ovf_cnt | ovf_list | slots
    const size_t HN = (size_t)BB * NN * HF;
    char* p = (char*)d_ws;
    int*    flags    = (int*)p;                       p += 64;
    ushort* wbf      = (ushort*)p;                    p += 32768 * 2;
    ushort* h        = (ushort*)p;                    p += HN * 2;
    float*  alpha_s  = (float*)p;                     p += (size_t)BB * NN * NH * 4;
    float*  alpha_d  = (float*)p;                     p += (size_t)BB * NN * NH * 4;
    float*  aw       = (float*)p;                     p += (size_t)BB * NN * NH * 4;
    int*    last_e   = (int*)p;                       p += (size_t)NN * 4;
    int*    cnt      = (int*)p;                       p += (size_t)NN * 4;
    int*    ovf_cnt  = (int*)p;                       p += 64;
    int*    ovf_list = (int*)p;                       p += (size_t)OVF_CAP * 4;
    ushort* slots    = (ushort*)p;

    k_init <<<(NN + 255) / 256, 256, 0, stream>>>((const ushort*)x, ei, W, flags, wbf,
                                                  cnt, last_e, ovf_cnt);
    k_gemm <<<EDGE_BLOCKS + GEMM_BLOCKS, 256, 0, stream>>>(x, wbf, a, ei, flags, h,
                                                           alpha_s, alpha_d, last_e,
                                                           cnt, slots, ovf_cnt, ovf_list);
    k_agg  <<<2048, 256, 0, stream>>>(slots, cnt, last_e, ei, flags,
                                      alpha_s, alpha_d, h, aw, out);
    k_fix  <<<32, 256, 0, stream>>>(ei, flags, ovf_cnt, ovf_list, h, aw, out);
}

// Round 3
// 152.268 us; speedup vs baseline: 1.0126x; 1.0085x over previous
//
#include <hip/hip_runtime.h>
#include <hip/hip_bf16.h>

#define BB 2
#define NN 20000
#define EE 200000
#define INF 256
#define OUTF 32
#define NH 4
#define HF 128          // NH*OUTF
#define NEG_SLOPE 0.2f
#define GEMM_BLOCKS 625  // 40000 rows / 64
#define EDGE_BLOCKS 782  // ceil(200000/256), 1 edge per thread
#define CAP 48           // uint slots per node (deg ~ Poisson(10); overflow -> list)
#define OVF_CAP 8192

using bf16 = __hip_bfloat16;
typedef __attribute__((ext_vector_type(8))) short bf16x8;
typedef __attribute__((ext_vector_type(4))) float f32x4;

__device__ __forceinline__ float bf2f(unsigned short s){ return __uint_as_float((unsigned)s << 16); }
__device__ __forceinline__ ushort f2bf_bits(float f){
    __hip_bfloat16 b = __float2bfloat16(f);
    return *(ushort*)&b;
}

__device__ __forceinline__ int get_src(const int* ei, int e, int f64){
    return f64 ? ei[2 * e] : ei[e];
}
__device__ __forceinline__ int get_dst(const int* ei, int e, int f64){
    return f64 ? ei[2 * EE + 2 * e] : ei[EE + e];
}

// K0: init cnt/last_e/ovf; blocks 0..15: dtype-detect (each block re-derives the
// flag from the same data -> deterministic) + W -> bf16 B-frag-linear wbf,
// one frag per thread (16 blocks x 256 threads = 4096 frags).
__global__ void k_init(const ushort* __restrict__ xr, const int* __restrict__ er,
                       const void* __restrict__ Wv,
                       int* __restrict__ flags, ushort* __restrict__ wbf,
                       int* __restrict__ cnt, int* __restrict__ last_e,
                       int* __restrict__ ovf_cnt){
    int i = blockIdx.x * blockDim.x + threadIdx.x;
    if (i < NN){ cnt[i] = 0; last_e[i] = -1; }
    if (i == 0) *ovf_cnt = 0;
    if (blockIdx.x < 16){
        __shared__ int cnt_big, cnt_nz;
        if (threadIdx.x == 0){ cnt_big = 0; cnt_nz = 0; }
        __syncthreads();
        int big = 0;
        for (int k = threadIdx.x; k < 8192; k += blockDim.x){
            unsigned e = ((unsigned)xr[2 * k] >> 7) & 0xff;   // bf16-exp of fp32 low half
            if (e >= 0xC0) big++;                              // impossible for N(0,1) bf16
        }
        int nz = 0;
        for (int k = threadIdx.x; k < 4096; k += blockDim.x){
            if (er[2 * k + 1] != 0) nz++;                      // int64 high words all zero
        }
        atomicAdd(&cnt_big, big);
        atomicAdd(&cnt_nz, nz);
        __syncthreads();
        if (blockIdx.x == 0 && threadIdx.x == 0){
            flags[0] = (cnt_big >= 16) ? 1 : 0;
            flags[1] = (cnt_nz == 0) ? 1 : 0;
        }
        const bool f32w = (cnt_big >= 16);
        int fr = blockIdx.x * 256 + threadIdx.x;               // 0..4095
        {
            int lane = fr & 63;
            int t    = (fr >> 6) & 3;
            int kc   = (fr >> 8) & 7;
            int ch   = fr >> 11;
            int col  = ch * 64 + t * 16 + (lane & 15);
            int kb   = kc * 32 + (lane >> 4) * 8;
            bf16x8 v;
            if (f32w){
                const float* wg = (const float*)Wv + (size_t)col * INF + kb;
                #pragma unroll
                for (int j = 0; j < 8; ++j) v[j] = (short)f2bf_bits(wg[j]);
            } else {
                const ushort* wg = (const ushort*)Wv + (size_t)col * INF + kb;
                #pragma unroll
                for (int j = 0; j < 8; ++j) v[j] = (short)wg[j];
            }
            *(bf16x8*)(wbf + (size_t)fr * 8) = v;
        }
    }
}

// K1: edge blocks FIRST: ONE atomic per edge (slot-allocating atomicAdd); the
// slot stores the EDGE ID, so last_e = max(slot values) falls out in k_agg.
// dst is never loaded here. Rare overflow path keeps a compensating atomicMax.
// Then MFMA GEMM, one wave = 16 rows x BOTH col-halves, 1-deep x pipeline.
__global__ __launch_bounds__(256, 2)
void k_gemm(const void* __restrict__ xv_, const ushort* __restrict__ wbf,
            const void* __restrict__ av, const int* __restrict__ ei,
            const int* __restrict__ flags, ushort* __restrict__ h,
            float* __restrict__ alpha_s, float* __restrict__ alpha_d,
            int* __restrict__ last_e, int* __restrict__ cnt,
            unsigned* __restrict__ slots, int* __restrict__ ovf_cnt,
            int* __restrict__ ovf_list){
    if (blockIdx.x < EDGE_BLOCKS){
        int f64 = flags[1];
        int e = blockIdx.x * 256 + threadIdx.x;
        if (e < EE){
            int s = get_src(ei, e, f64);
            int idx = atomicAdd(&cnt[s], 1);
            if (idx < CAP) slots[(size_t)s * CAP + idx] = (unsigned)e;
            else {
                atomicMax(&last_e[s], e);   // rare: keeps le correct past CAP
                int o = atomicAdd(ovf_cnt, 1);
                if (o < OVF_CAP) ovf_list[o] = e;
            }
        }
        return;
    }

    const int bid  = blockIdx.x - EDGE_BLOCKS;
    const int tid  = threadIdx.x;
    const int lane = tid & 63;
    const int w    = tid >> 6;            // wave 0..3
    const int l15  = lane & 15;
    const int q    = lane >> 4;           // quad 0..3
    const bool f32 = flags[0] != 0;

    const int row0 = bid * 64 + w * 16;   // wave's 16 rows

    f32x4 acc[2][4];
    #pragma unroll
    for (int c = 0; c < 2; ++c)
        #pragma unroll
        for (int t = 0; t < 4; ++t) acc[c][t] = (f32x4){0.f, 0.f, 0.f, 0.f};

    if (f32){
        const float* xp = (const float*)xv_ + (size_t)(row0 + l15) * INF + q * 8;
        // 1-deep pipeline: cur pair in regs, next pair in flight.
        float4 c0 = ((const float4*)xp)[0];
        float4 c1 = ((const float4*)xp)[1];
        #pragma unroll
        for (int kc = 0; kc < 8; ++kc){
            float4 n0, n1;
            if (kc < 7){
                const float4* p = (const float4*)(xp + (kc + 1) * 32);
                n0 = p[0];
                n1 = p[1];
            }
            bf16x8 afrag;
            afrag[0] = (short)f2bf_bits(c0.x); afrag[1] = (short)f2bf_bits(c0.y);
            afrag[2] = (short)f2bf_bits(c0.z); afrag[3] = (short)f2bf_bits(c0.w);
            afrag[4] = (short)f2bf_bits(c1.x); afrag[5] = (short)f2bf_bits(c1.y);
            afrag[6] = (short)f2bf_bits(c1.z); afrag[7] = (short)f2bf_bits(c1.w);
            #pragma unroll
            for (int c = 0; c < 2; ++c){
                const ushort* wb = wbf + (size_t)c * 16384;
                #pragma unroll
                for (int t = 0; t < 4; ++t){
                    bf16x8 bfrag = *(const bf16x8*)(wb + (((size_t)kc * 4 + t) * 64 + lane) * 8);
                    acc[c][t] = __builtin_amdgcn_mfma_f32_16x16x32_bf16(afrag, bfrag, acc[c][t], 0, 0, 0);
                }
            }
            if (kc < 7){ c0 = n0; c1 = n1; }
        }
    } else {
        const ushort* xp = (const ushort*)xv_ + (size_t)(row0 + l15) * INF + q * 8;
        bf16x8 af = *(const bf16x8*)xp;
        #pragma unroll
        for (int kc = 0; kc < 8; ++kc){
            bf16x8 nf;
            if (kc < 7) nf = *(const bf16x8*)(xp + (kc + 1) * 32);
            #pragma unroll
            for (int c = 0; c < 2; ++c){
                const ushort* wb = wbf + (size_t)c * 16384;
                #pragma unroll
                for (int t = 0; t < 4; ++t){
                    bf16x8 bfrag = *(const bf16x8*)(wb + (((size_t)kc * 4 + t) * 64 + lane) * 8);
                    acc[c][t] = __builtin_amdgcn_mfma_f32_16x16x32_bf16(af, bfrag, acc[c][t], 0, 0, 0);
                }
            }
            if (kc < 7) af = nf;
        }
    }

    // ---- epilogue 1: h -> bf16, f-major [row][f*4+hd]; both col-halves -> one 8B store ----
    #pragma unroll
    for (int r = 0; r < 4; ++r){
        int row = row0 + q * 4 + r;
        #pragma unroll
        for (int t = 0; t < 2; ++t){    // t = f-half; f = t*16 + l15
            unsigned v0 = (unsigned)f2bf_bits(acc[0][t][r])
                        | ((unsigned)f2bf_bits(acc[0][t + 2][r]) << 16);  // heads 0,1
            unsigned v1 = (unsigned)f2bf_bits(acc[1][t][r])
                        | ((unsigned)f2bf_bits(acc[1][t + 2][r]) << 16);  // heads 2,3
            int f = t * 16 + l15;
            uint2 vv; vv.x = v0; vv.y = v1;
            *(uint2*)(h + (size_t)row * HF + f * 4) = vv;
        }
    }

    // ---- epilogue 2: alpha dots from C registers ----
    float as_lo, as_hi, ad_lo, ad_hi;
    if (f32){
        const float* af = (const float*)av;
        as_lo = af[l15];        as_hi = af[16 + l15];
        ad_lo = af[OUTF + l15]; ad_hi = af[OUTF + 16 + l15];
    } else {
        const ushort* ab = (const ushort*)av;
        as_lo = bf2f(ab[l15]);        as_hi = bf2f(ab[16 + l15]);
        ad_lo = bf2f(ab[OUTF + l15]); ad_hi = bf2f(ab[OUTF + 16 + l15]);
    }
    #pragma unroll
    for (int r = 0; r < 4; ++r){
        int row = row0 + q * 4 + r;
        #pragma unroll
        for (int c = 0; c < 2; ++c){
            #pragma unroll
            for (int hp = 0; hp < 2; ++hp){
                int t0 = hp * 2, t1 = hp * 2 + 1;
                float ps = acc[c][t0][r] * as_lo + acc[c][t1][r] * as_hi;
                float pd = acc[c][t0][r] * ad_lo + acc[c][t1][r] * ad_hi;
                ps += __shfl_down(ps, 8, 16); pd += __shfl_down(pd, 8, 16);
                ps += __shfl_down(ps, 4, 16); pd += __shfl_down(pd, 4, 16);
                ps += __shfl_down(ps, 2, 16); pd += __shfl_down(pd, 2, 16);
                ps += __shfl_down(ps, 1, 16); pd += __shfl_down(pd, 1, 16);
                if (l15 == 0){
                    size_t o = (size_t)row * NH + c * 2 + hp;
                    alpha_s[o] = ps;
                    alpha_d[o] = pd;
                }
            }
        }
    }
}

// K2 (fused aw+agg): one wave per node. Walk bucket of EDGE IDS: recover dst via
// uniform L2 gather dst[e], accumulate h rows, and track le = max(e) on the fly
// (combined with last_e[n] for the rare overflow case). Then per-(b,h) batch
// softmax at le (lanes 0..7, broadcast via shfl); aw kept in global for k_fix.
__global__ __launch_bounds__(256)
void k_agg(const unsigned* __restrict__ slots, const int* __restrict__ cnt,
           const int* __restrict__ last_e, const int* __restrict__ ei,
           const int* __restrict__ flags,
           const float* __restrict__ alpha_s, const float* __restrict__ alpha_d,
           const ushort* __restrict__ h, float* __restrict__ aw,
           float* __restrict__ out_f){
    int lane = threadIdx.x & 63;
    int wid  = (blockIdx.x * blockDim.x + threadIdx.x) >> 6;
    int nw   = (gridDim.x * blockDim.x) >> 6;
    int b = lane >> 5;
    int f = lane & 31;
    int c  = lane & 7;          // softmax work item: bb = c>>2, hh = c&3
    int bb = c >> 2;
    int hh = c & 3;
    int f64 = flags[1];
    for (int n = wid; n < NN; n += nw){
        int m  = cnt[n]; if (m > CAP) m = CAP;
        int le = last_e[n];                       // -1 unless overflow happened

        const unsigned* sl = slots + (size_t)n * CAP;
        const ushort* hb = h + (size_t)b * NN * HF + f * 4;
        float ax = 0.f, ay = 0.f, az = 0.f, aww = 0.f;
        int i = 0;
        for (; i + 4 <= m; i += 4){
            uint4 ee = *(const uint4*)(sl + i);     // uniform 16B broadcast
            le = max(le, (int)ee.x); le = max(le, (int)ee.y);
            le = max(le, (int)ee.z); le = max(le, (int)ee.w);
            int d0 = get_dst(ei, (int)ee.x, f64);
            int d1 = get_dst(ei, (int)ee.y, f64);
            int d2 = get_dst(ei, (int)ee.z, f64);
            int d3 = get_dst(ei, (int)ee.w, f64);
            ushort4 u0 = *(const ushort4*)(hb + (size_t)d0 * HF);
            ushort4 u1 = *(const ushort4*)(hb + (size_t)d1 * HF);
            ushort4 u2 = *(const ushort4*)(hb + (size_t)d2 * HF);
            ushort4 u3 = *(const ushort4*)(hb + (size_t)d3 * HF);
            ax += bf2f(u0.x) + bf2f(u1.x) + bf2f(u2.x) + bf2f(u3.x);
            ay += bf2f(u0.y) + bf2f(u1.y) + bf2f(u2.y) + bf2f(u3.y);
            az += bf2f(u0.z) + bf2f(u1.z) + bf2f(u2.z) + bf2f(u3.z);
            aww += bf2f(u0.w) + bf2f(u1.w) + bf2f(u2.w) + bf2f(u3.w);
        }
        for (; i < m; ++i){
            int e = (int)sl[i];
            le = max(le, e);
            int d = get_dst(ei, e, f64);
            ushort4 u = *(const ushort4*)(hb + (size_t)d * HF);
            ax += bf2f(u.x); ay += bf2f(u.y); az += bf2f(u.z); aww += bf2f(u.w);
        }

        // per-(bb,hh) attention weight (replicated x8 across the wave)
        float my_aw = 0.f;
        if (le >= 0){
            int d = get_dst(ei, le, f64);
            float ss = alpha_s[((size_t)bb * NN + n) * NH + hh]
                     + alpha_d[((size_t)bb * NN + d) * NH + hh];
            float so = alpha_s[((size_t)(1 - bb) * NN + n) * NH + hh]
                     + alpha_d[((size_t)(1 - bb) * NN + d) * NH + hh];
            ss = ss > 0.f ? ss : NEG_SLOPE * ss;
            so = so > 0.f ? so : NEG_SLOPE * so;
            float mx = fmaxf(ss, so);
            float e0 = __expf(ss - mx);
            float e1 = __expf(so - mx);
            my_aw = 0.25f * e0 / (e0 + e1);
        }
        if (lane < 8) aw[((size_t)bb * NN + n) * NH + hh] = my_aw;  // for k_fix

        float aw0 = __shfl(my_aw, (b << 2) + 0, 8);
        float aw1 = __shfl(my_aw, (b << 2) + 1, 8);
        float aw2 = __shfl(my_aw, (b << 2) + 2, 8);
        float aw3 = __shfl(my_aw, (b << 2) + 3, 8);

        out_f[((size_t)b * NN + n) * OUTF + f] =
            aw0 * ax + aw1 * ay + aw2 * az + aw3 * aww;
    }
}

// K4: overflow fix-up (normally empty). One wave per overflow edge, atomics.
__global__ void k_fix(const int* __restrict__ ei, const int* __restrict__ flags,
                      const int* __restrict__ ovf_cnt, const int* __restrict__ ovf_list,
                      const ushort* __restrict__ h, const float* __restrict__ aw,
                      float* __restrict__ out_f){
    int lane = threadIdx.x & 63;
    int wid  = (blockIdx.x * blockDim.x + threadIdx.x) >> 6;
    int nw   = (gridDim.x * blockDim.x) >> 6;
    int b = lane >> 5;
    int f = lane & 31;
    int M = *ovf_cnt; if (M > OVF_CAP) M = OVF_CAP;
    int f64 = flags[1];
    for (int i = wid; i < M; i += nw){
        int e = ovf_list[i];
        int s = get_src(ei, e, f64);
        int d = get_dst(ei, e, f64);
        float4 awv = *(const float4*)(aw + ((size_t)b * NN + s) * NH);
        ushort4 u = *(const ushort4*)(h + ((size_t)b * NN + d) * HF + f * 4);
        float acc = awv.x * bf2f(u.x) + awv.y * bf2f(u.y)
                  + awv.z * bf2f(u.z) + awv.w * bf2f(u.w);
        atomicAdd(&out_f[((size_t)b * NN + s) * OUTF + f], acc);
    }
}

extern "C" void kernel_launch(void* const* d_in, const int* in_sizes, int n_in,
                              void* d_out, int out_size, void* d_ws, size_t ws_size,
                              hipStream_t stream){
    const void* x = d_in[0]; const void* eiv = d_in[1];
    const void* W = d_in[2]; const void* a  = d_in[3];
    for (int i = 0; i < n_in; ++i){
        if      (in_sizes[i] == BB * NN * INF) x   = d_in[i];
        else if (in_sizes[i] == 2 * EE)        eiv = d_in[i];
        else if (in_sizes[i] == HF * INF)      W   = d_in[i];
        else if (in_sizes[i] == 2 * OUTF)      a   = d_in[i];
    }
    const int* ei = (const int*)eiv;
    float* out = (float*)d_out;    // output dtype: float32 (verified round 3)

    // Workspace (~15.5 MiB): flags | wbf | h | alpha_s | alpha_d | aw | last_e
    //                        | cnt | ovf_cnt | ovf_list | slots (uint, CAP=48 ->
    //                        same 192 B/node footprint as the old ushort CAP=96)
    const size_t HN = (size_t)BB * NN * HF;
    char* p = (char*)d_ws;
    int*      flags    = (int*)p;                     p += 64;
    ushort*   wbf      = (ushort*)p;                  p += 32768 * 2;
    ushort*   h        = (ushort*)p;                  p += HN * 2;
    float*    alpha_s  = (float*)p;                   p += (size_t)BB * NN * NH * 4;
    float*    alpha_d  = (float*)p;                   p += (size_t)BB * NN * NH * 4;
    float*    aw       = (float*)p;                   p += (size_t)BB * NN * NH * 4;
    int*      last_e   = (int*)p;                     p += (size_t)NN * 4;
    int*      cnt      = (int*)p;                     p += (size_t)NN * 4;
    int*      ovf_cnt  = (int*)p;                     p += 64;
    int*      ovf_list = (int*)p;                     p += (size_t)OVF_CAP * 4;
    unsigned* slots    = (unsigned*)p;

    k_init <<<(NN + 255) / 256, 256, 0, stream>>>((const ushort*)x, ei, W, flags, wbf,
                                                  cnt, last_e, ovf_cnt);
    k_gemm <<<EDGE_BLOCKS + GEMM_BLOCKS, 256, 0, stream>>>(x, wbf, a, ei, flags, h,
                                                           alpha_s, alpha_d, last_e,
                                                           cnt, slots, ovf_cnt, ovf_list);
    k_agg  <<<2048, 256, 0, stream>>>(slots, cnt, last_e, ei, flags,
                                      alpha_s, alpha_d, h, aw, out);
    k_fix  <<<32, 256, 0, stream>>>(ei, flags, ovf_cnt, ovf_list, h, aw, out);
}